// Round 1
// baseline (2946.020 us; speedup 1.0000x reference)
//
#include <hip/hip_runtime.h>
#include <hip/hip_bf16.h>
#include <stdint.h>

#define TOK 8192      // B*N tokens
#define DIM 1024
#define NSEQ 4096
#define NH 8
#define DHD 128
#define NU 64         // buckets
#define DFF 4096
#define NBH 16        // B*H

typedef unsigned short u16;
typedef unsigned int u32;
typedef short bf16x8 __attribute__((ext_vector_type(8)));
typedef float f32x4 __attribute__((ext_vector_type(4)));

__device__ __forceinline__ float bu2f(u16 u) { return __uint_as_float(((u32)u) << 16); }
__device__ __forceinline__ u16 f2bu(float f) {
  union { __hip_bfloat16 b; u16 u; } cv; cv.b = __float2bfloat16(f); return cv.u;
}

typedef __attribute__((address_space(1))) void gvoid_t;
typedef __attribute__((address_space(3))) void lvoid_t;
__device__ __forceinline__ void gload16(void* lds, const void* g) {
#if __has_builtin(__builtin_amdgcn_global_load_lds)
  __builtin_amdgcn_global_load_lds((const gvoid_t*)g, (lvoid_t*)lds, 16, 0, 0);
#else
  const int l = threadIdx.x & 63;
  ((uint4*)lds)[l] = *(const uint4*)g;
#endif
}

// ---------------- weight transpose + fp32->bf16 : W[K][N] -> Wt[N][K] ----------------
__global__ __launch_bounds__(256) void wtrans_kernel(const float* __restrict__ W,
    u16* __restrict__ Wt, int K, int N)
{
  __shared__ float T[32][33];
  const int tid = threadIdx.x;
  const size_t doff = (size_t)blockIdx.z * K * N;
  const int n0 = blockIdx.x << 5, k0 = blockIdx.y << 5;
  const int r = tid >> 3, c4 = (tid & 7) << 2;
  float4 v = *(const float4*)(W + doff + (size_t)(k0 + r) * N + n0 + c4);
  T[r][c4] = v.x; T[r][c4 + 1] = v.y; T[r][c4 + 2] = v.z; T[r][c4 + 3] = v.w;
  __syncthreads();
  u32 lo = (u32)f2bu(T[c4][r]) | ((u32)f2bu(T[c4 + 1][r]) << 16);
  u32 hi = (u32)f2bu(T[c4 + 2][r]) | ((u32)f2bu(T[c4 + 3][r]) << 16);
  *(uint2*)(Wt + doff + (size_t)(n0 + r) * K + k0 + c4) = make_uint2(lo, hi);
}

// ---------------- layernorm fp32 -> bf16 ----------------
__global__ __launch_bounds__(256) void ln_kernel(const float* __restrict__ x,
    const float* __restrict__ g, const float* __restrict__ bt, u16* __restrict__ h)
{
  const int row = blockIdx.x, tid = threadIdx.x;
  const int w = tid >> 6, l = tid & 63;
  float4 v = ((const float4*)(x + (size_t)row * DIM))[tid];
  float s = v.x + v.y + v.z + v.w;
  float s2 = v.x * v.x + v.y * v.y + v.z * v.z + v.w * v.w;
#pragma unroll
  for (int off = 32; off; off >>= 1) { s += __shfl_down(s, off); s2 += __shfl_down(s2, off); }
  __shared__ float ps[8];
  __shared__ float mv[2];
  if (l == 0) { ps[w] = s; ps[4 + w] = s2; }
  __syncthreads();
  if (tid == 0) {
    float S = ps[0] + ps[1] + ps[2] + ps[3];
    float S2 = ps[4] + ps[5] + ps[6] + ps[7];
    float mean = S * (1.f / 1024.f);
    float var = S2 * (1.f / 1024.f) - mean * mean;
    mv[0] = mean; mv[1] = rsqrtf(var + 1e-5f);
  }
  __syncthreads();
  const float mean = mv[0], inv = mv[1];
  const int c = tid * 4;
  float o0 = (v.x - mean) * inv * g[c + 0] + bt[c + 0];
  float o1 = (v.y - mean) * inv * g[c + 1] + bt[c + 1];
  float o2 = (v.z - mean) * inv * g[c + 2] + bt[c + 2];
  float o3 = (v.w - mean) * inv * g[c + 3] + bt[c + 3];
  u32 lo = (u32)f2bu(o0) | ((u32)f2bu(o1) << 16);
  u32 hi = (u32)f2bu(o2) | ((u32)f2bu(o3) << 16);
  ((uint2*)(h + (size_t)row * DIM))[tid] = make_uint2(lo, hi);
}

// ---------------- bf16 GEMM, m97 structure: A[M][K] x Bt[N][K] -> C[M][N] ----------------
// EPI 0: C=AB -> bf16 ; EPI 1: C=AB+bias+res -> f32 ; EPI 2: C=gelu(AB+bias) -> bf16
template<int EPI>
__global__ __launch_bounds__(256, 2) void gemm_kernel(
    const u16* __restrict__ A, const u16* __restrict__ Bt, void* Cout,
    const float* __restrict__ bias, const float* res, int M, int N, int K)
{
  __shared__ __align__(16) u16 As[2][128 * 32];
  __shared__ __align__(16) u16 Bs[2][128 * 32];
  const int tid = threadIdx.x;
  const int w = tid >> 6, l = tid & 63;
  const int brow = blockIdx.y << 7, bcol = blockIdx.x << 7;
  const int wr = (w >> 1) << 6, wc = (w & 1) << 6;
  const int lr = l & 15, lk = (l >> 4) << 3;
  f32x4 acc[4][4] = {};
  const int nk = K >> 5;

#define STAGE_G(buf, kt)                                                        \
  {                                                                             \
    _Pragma("unroll")                                                           \
    for (int j = 0; j < 2; ++j) {                                               \
      int c = j * 256 + tid;                                                    \
      int rrow = c >> 2, k8 = (c & 3) << 3;                                     \
      int ub = (j * 256 + w * 64) * 8;                                          \
      gload16(&As[buf][ub], A + (size_t)(brow + rrow) * K + (kt) * 32 + k8);    \
      gload16(&Bs[buf][ub], Bt + (size_t)(bcol + rrow) * K + (kt) * 32 + k8);   \
    }                                                                           \
  }

  STAGE_G(0, 0);
  __syncthreads();
  for (int kt = 0; kt < nk; ++kt) {
    int buf = kt & 1;
    if (kt + 1 < nk) STAGE_G(buf ^ 1, kt + 1);
    bf16x8 a[4], bb[4];
#pragma unroll
    for (int m = 0; m < 4; ++m) a[m] = *(const bf16x8*)&As[buf][(wr + m * 16 + lr) * 32 + lk];
#pragma unroll
    for (int n = 0; n < 4; ++n) bb[n] = *(const bf16x8*)&Bs[buf][(wc + n * 16 + lr) * 32 + lk];
#pragma unroll
    for (int m = 0; m < 4; ++m)
#pragma unroll
      for (int n = 0; n < 4; ++n)
        acc[m][n] = __builtin_amdgcn_mfma_f32_16x16x32_bf16(a[m], bb[n], acc[m][n], 0, 0, 0);
    __syncthreads();
  }
#undef STAGE_G
  const int l4 = (l >> 4) << 2;
#pragma unroll
  for (int m = 0; m < 4; ++m) {
#pragma unroll
    for (int n = 0; n < 4; ++n) {
      int col = bcol + wc + n * 16 + lr;
#pragma unroll
      for (int r = 0; r < 4; ++r) {
        int row = brow + wr + m * 16 + l4 + r;
        size_t idx = (size_t)row * N + col;
        float v0 = acc[m][n][r];
        if (EPI == 0) {
          ((u16*)Cout)[idx] = f2bu(v0);
        } else if (EPI == 1) {
          ((float*)Cout)[idx] = v0 + bias[col] + res[idx];
        } else {
          float t = v0 + bias[col];
          ((u16*)Cout)[idx] = f2bu(0.5f * t * (1.0f + erff(t * 0.70710678118654752f)));
        }
      }
    }
  }
}

// ---------------- attention: q softmax (rows of 128 contiguous) ----------------
__global__ __launch_bounds__(256) void qsoftmax_kernel(const u16* __restrict__ q, u16* __restrict__ qs)
{
  const int w = threadIdx.x >> 6, l = threadIdx.x & 63;
  const size_t gid = (size_t)blockIdx.x * 4 + w;
  const u16* row = q + gid * 128;
  u16* orow = qs + gid * 128;
  u32 p = *(const u32*)(row + l * 2);
  float f0 = bu2f((u16)(p & 0xffff)), f1 = bu2f((u16)(p >> 16));
  float m = fmaxf(f0, f1);
#pragma unroll
  for (int off = 32; off; off >>= 1) m = fmaxf(m, __shfl_xor(m, off));
  float e0 = expf(f0 - m), e1 = expf(f1 - m);
  float s = e0 + e1;
#pragma unroll
  for (int off = 32; off; off >>= 1) s += __shfl_xor(s, off);
  float sc = 0.08838834764831845f / s;   // (1/sqrt(128)) / sum
  u32 o = (u32)f2bu(e0 * sc) | ((u32)f2bu(e1 * sc) << 16);
  *(u32*)(orow + l * 2) = o;
}

// ---------------- exp(k), v : [b,n,h*128+e] -> transposed [bh][e][n] bf16 ----------------
__global__ __launch_bounds__(256) void kvt_kernel(
    const u16* __restrict__ kin, const u16* __restrict__ vin,
    u16* __restrict__ ket, u16* __restrict__ vt)
{
  __shared__ u16 T[128 * 72];
  const int tid = threadIdx.x;
  const int t64 = blockIdx.x, bh = blockIdx.y;
  const int b = bh >> 3, h = bh & 7;
  for (int pass = 0; pass < 2; ++pass) {
    const u16* src = pass ? vin : kin;
    u16* dst = pass ? vt : ket;
    if (pass) __syncthreads();
#pragma unroll
    for (int j = 0; j < 4; ++j) {
      int c = j * 256 + tid;
      int i = c >> 4, e8 = (c & 15) << 3;
      bf16x8 dv = *(const bf16x8*)(src + ((size_t)(b * NSEQ + t64 * 64 + i)) * DIM + h * 128 + e8);
#pragma unroll
      for (int jj = 0; jj < 8; ++jj) {
        float f = bu2f((u16)dv[jj]);
        if (pass == 0) f = expf(f);
        T[(e8 + jj) * 72 + i] = f2bu(f);
      }
    }
    __syncthreads();
#pragma unroll
    for (int j = 0; j < 4; ++j) {
      int c = j * 256 + tid;
      int e = c >> 3, n8 = (c & 7) << 3;
      bf16x8 o;
#pragma unroll
      for (int jj = 0; jj < 8; ++jj) o[jj] = (short)T[e * 72 + n8 + jj];
      *(bf16x8*)(dst + ((size_t)(bh * 128 + e)) * NSEQ + t64 * 64 + n8) = o;
    }
  }
}

// ---------------- per-bucket k sums ----------------
__global__ void ksum_kernel(const u16* __restrict__ ket, float* __restrict__ Ksum)
{
  const int u = blockIdx.x, bh = blockIdx.y, e = threadIdx.x;  // 128 threads
  const u16* p = ket + ((size_t)(bh * 128 + e)) * NSEQ + u * 64;
  float s = 0.f;
#pragma unroll
  for (int i = 0; i < 64; ++i) s += bu2f(p[i]);
  Ksum[(((size_t)bh * 64 + u) << 7) + e] = s;
}

// ---------------- exclusive cumsum of k sums over buckets ----------------
__global__ void kc_kernel(const float* __restrict__ Ksum, float* __restrict__ Kc)
{
  const int bh = blockIdx.x, e = threadIdx.x;
  float run = 0.f;
  for (int u = 0; u < 64; ++u) {
    size_t i = (((size_t)bh * 64 + u) << 7) + e;
    Kc[i] = run;
    run += Ksum[i];
  }
}

// ---------------- per-bucket ctx^T[e][d] = sum_i v[i,e]*ke[i,d] (MFMA) ----------------
__global__ __launch_bounds__(256, 2) void ctx_kernel(
    const u16* __restrict__ vt, const u16* __restrict__ ket, u16* __restrict__ ctxT)
{
  __shared__ __align__(16) u16 Av[128 * 64];
  __shared__ __align__(16) u16 Bk[128 * 64];
  const int tid = threadIdx.x, w = tid >> 6, l = tid & 63;
  const int u = blockIdx.x, bh = blockIdx.y;
  const int lr = l & 15, lk = (l >> 4) << 3;
#pragma unroll
  for (int j = 0; j < 4; ++j) {
    int c = j * 256 + tid;
    int row = c >> 3, i8 = (c & 7) << 3;
    size_t goff = ((size_t)(bh * 128 + row)) * NSEQ + u * 64 + i8;
    int ub = (j * 256 + w * 64) * 8;
    gload16(&Av[ub], vt + goff);
    gload16(&Bk[ub], ket + goff);
  }
  __syncthreads();
  const int wr = (w >> 1) << 6, wc = (w & 1) << 6;
  f32x4 acc[4][4] = {};
#pragma unroll
  for (int ks = 0; ks < 2; ++ks) {
    bf16x8 a[4], bb[4];
#pragma unroll
    for (int m = 0; m < 4; ++m) a[m] = *(const bf16x8*)&Av[(wr + m * 16 + lr) * 64 + ks * 32 + lk];
#pragma unroll
    for (int n = 0; n < 4; ++n) bb[n] = *(const bf16x8*)&Bk[(wc + n * 16 + lr) * 64 + ks * 32 + lk];
#pragma unroll
    for (int m = 0; m < 4; ++m)
#pragma unroll
      for (int n = 0; n < 4; ++n)
        acc[m][n] = __builtin_amdgcn_mfma_f32_16x16x32_bf16(a[m], bb[n], acc[m][n], 0, 0, 0);
  }
  u16* out = ctxT + ((size_t)(bh * 64 + u) << 14);
  const int l4 = (l >> 4) << 2;
#pragma unroll
  for (int m = 0; m < 4; ++m)
#pragma unroll
    for (int n = 0; n < 4; ++n)
#pragma unroll
      for (int r = 0; r < 4; ++r) {
        int e = wr + m * 16 + l4 + r, d = wc + n * 16 + lr;
        out[e * 128 + d] = f2bu(acc[m][n][r]);
      }
}

// ---------------- exclusive cumsum of ctx over buckets ----------------
__global__ void cumsum_kernel(const u16* __restrict__ ctxT, u16* __restrict__ ctxc)
{
  const size_t base = ((size_t)blockIdx.y << 20) + (size_t)blockIdx.x * 256 + threadIdx.x;
  const u16* src = ctxT + base;
  u16* dst = ctxc + base;
  float run = 0.f;
  for (int u = 0; u < 64; ++u) {
    u16 cvv = src[(size_t)u << 14];
    dst[(size_t)u << 14] = f2bu(run);
    run += bu2f(cvv);
  }
}

// ---------------- out[n][e] = D_inv[n] * sum_d qs[n,d]*ctxc[d][e] (MFMA) ----------------
__global__ __launch_bounds__(256, 2) void attnout_kernel(
    const u16* __restrict__ qs, const u16* __restrict__ ctxc,
    const float* __restrict__ Kc, u16* __restrict__ aout)
{
  __shared__ __align__(16) u16 Aq[64 * 128];
  __shared__ __align__(16) u16 Bc[128 * 128];
  __shared__ float KcS[128];
  __shared__ float Dinv[64];
  const int tid = threadIdx.x, w = tid >> 6, l = tid & 63;
  const int u = blockIdx.x, bh = blockIdx.y;
  const int b = bh >> 3, h = bh & 7;
  const int lr = l & 15, lk = (l >> 4) << 3;
#pragma unroll
  for (int j = 0; j < 4; ++j) {
    int c = j * 256 + tid;
    int n = c >> 4, d8 = (c & 15) << 3;
    gload16(&Aq[(j * 256 + w * 64) * 8],
            qs + ((size_t)(b * NSEQ + u * 64 + n)) * DIM + h * 128 + d8);
  }
  const u16* csrc = ctxc + ((size_t)(bh * 64 + u) << 14);
#pragma unroll
  for (int j = 0; j < 8; ++j) {
    int c = j * 256 + tid;
    gload16(&Bc[(j * 256 + w * 64) * 8], csrc + (size_t)c * 8);
  }
  if (tid < 128) KcS[tid] = Kc[(((size_t)bh * 64 + u) << 7) + tid];
  __syncthreads();
  if (tid < 64) {
    float s = 0.f;
#pragma unroll
    for (int dd = 0; dd < 128; ++dd) {
      int d = (dd + tid * 2) & 127;   // rotate to dodge LDS bank conflicts
      s += bu2f(Aq[tid * 128 + d]) * KcS[d];
    }
    Dinv[tid] = 1.f / fmaxf(s, 1e-3f);
  }
  __syncthreads();
  f32x4 acc[4][2] = {};
#pragma unroll
  for (int ks = 0; ks < 4; ++ks) {
    bf16x8 a[4], bb[2];
#pragma unroll
    for (int m = 0; m < 4; ++m) a[m] = *(const bf16x8*)&Aq[(m * 16 + lr) * 128 + ks * 32 + lk];
#pragma unroll
    for (int n = 0; n < 2; ++n) bb[n] = *(const bf16x8*)&Bc[(w * 32 + n * 16 + lr) * 128 + ks * 32 + lk];
#pragma unroll
    for (int m = 0; m < 4; ++m)
#pragma unroll
      for (int n = 0; n < 2; ++n)
        acc[m][n] = __builtin_amdgcn_mfma_f32_16x16x32_bf16(a[m], bb[n], acc[m][n], 0, 0, 0);
  }
  const int l4 = (l >> 4) << 2;
#pragma unroll
  for (int m = 0; m < 4; ++m)
#pragma unroll
    for (int n = 0; n < 2; ++n)
#pragma unroll
      for (int r = 0; r < 4; ++r) {
        int nrow = m * 16 + l4 + r;
        int e = w * 32 + n * 16 + lr;
        float v = acc[m][n][r] * Dinv[nrow];
        aout[((size_t)(b * NSEQ + u * 64 + nrow)) * DIM + h * 128 + e] = f2bu(v);
      }
}

extern "C" void kernel_launch(void* const* d_in, const int* in_sizes, int n_in,
                              void* d_out, int out_size, void* d_ws, size_t ws_size,
                              hipStream_t stream)
{
  (void)in_sizes; (void)n_in; (void)out_size; (void)ws_size;
  const float* x_in = (const float*)d_in[0];
  const float* ln1g = (const float*)d_in[1];
  const float* ln1b = (const float*)d_in[2];
  const float* Wq   = (const float*)d_in[3];
  const float* Wk   = (const float*)d_in[4];
  const float* Wv   = (const float*)d_in[5];
  const float* Wo   = (const float*)d_in[6];
  const float* bo   = (const float*)d_in[7];
  const float* ln2g = (const float*)d_in[8];
  const float* ln2b = (const float*)d_in[9];
  const float* W1   = (const float*)d_in[10];
  const float* b1   = (const float*)d_in[11];
  const float* W2   = (const float*)d_in[12];
  const float* b2   = (const float*)d_in[13];
  float* x = (float*)d_out;

  char* ws = (char*)d_ws;
  size_t off = 0;
  auto alloc = [&](size_t bytes) -> char* {
    char* p = ws + off;
    off += (bytes + 255) & ~(size_t)255;
    return p;
  };
  const size_t SW = (size_t)6 * 1024 * 1024;   // small weight elems (per 6 layers)
  const size_t BW = (size_t)6 * 4096 * 1024;   // big weight elems
  u16* Wqt = (u16*)alloc(SW * 2);
  u16* Wkt = (u16*)alloc(SW * 2);
  u16* Wvt = (u16*)alloc(SW * 2);
  u16* Wot = (u16*)alloc(SW * 2);
  u16* W1t = (u16*)alloc(BW * 2);
  u16* W2t = (u16*)alloc(BW * 2);
  u16* hbuf = (u16*)alloc((size_t)TOK * DIM * 2);
  u16* qsb  = (u16*)alloc((size_t)TOK * DIM * 2);
  u16* ket  = (u16*)alloc((size_t)TOK * DIM * 2);
  u16* vtb  = (u16*)alloc((size_t)TOK * DIM * 2);
  u16* ab   = (u16*)alloc((size_t)TOK * DIM * 2);
  float* Ksum = (float*)alloc((size_t)NBH * 64 * 128 * 4);
  float* Kc   = (float*)alloc((size_t)NBH * 64 * 128 * 4);
  char* R = alloc((size_t)TOK * DFF * 2);      // 67MB union region
  u16* qb   = (u16*)R;                                   // phase 1: qkv bf16
  u16* kb   = (u16*)(R + (size_t)TOK * DIM * 2);
  u16* vb   = (u16*)(R + (size_t)TOK * DIM * 4);
  u16* ctxT = (u16*)R;                                   // phase 2: ctx buffers
  u16* ctxc = (u16*)(R + ((size_t)NBH * 64 * 128 * 128) * 2);
  u16* mid  = (u16*)R;                                   // phase 3: ffn mid

  // one-time (per call) weight transpose + bf16 conversion
  wtrans_kernel<<<dim3(32, 32, 6), 256, 0, stream>>>(Wq, Wqt, 1024, 1024);
  wtrans_kernel<<<dim3(32, 32, 6), 256, 0, stream>>>(Wk, Wkt, 1024, 1024);
  wtrans_kernel<<<dim3(32, 32, 6), 256, 0, stream>>>(Wv, Wvt, 1024, 1024);
  wtrans_kernel<<<dim3(32, 32, 6), 256, 0, stream>>>(Wo, Wot, 1024, 1024);
  wtrans_kernel<<<dim3(128, 32, 6), 256, 0, stream>>>(W1, W1t, 1024, 4096);
  wtrans_kernel<<<dim3(32, 128, 6), 256, 0, stream>>>(W2, W2t, 4096, 1024);
  hipMemcpyAsync(x, x_in, (size_t)TOK * DIM * 4, hipMemcpyDeviceToDevice, stream);

  for (int d = 0; d < 6; ++d) {
    ln_kernel<<<TOK, 256, 0, stream>>>(x, ln1g + d * DIM, ln1b + d * DIM, hbuf);
    gemm_kernel<0><<<dim3(8, 64), 256, 0, stream>>>(hbuf, Wqt + (size_t)d * 1024 * 1024, qb, nullptr, nullptr, TOK, DIM, DIM);
    gemm_kernel<0><<<dim3(8, 64), 256, 0, stream>>>(hbuf, Wkt + (size_t)d * 1024 * 1024, kb, nullptr, nullptr, TOK, DIM, DIM);
    gemm_kernel<0><<<dim3(8, 64), 256, 0, stream>>>(hbuf, Wvt + (size_t)d * 1024 * 1024, vb, nullptr, nullptr, TOK, DIM, DIM);
    qsoftmax_kernel<<<TOK * NH / 4, 256, 0, stream>>>(qb, qsb);
    kvt_kernel<<<dim3(64, NBH), 256, 0, stream>>>(kb, vb, ket, vtb);
    ksum_kernel<<<dim3(64, NBH), 128, 0, stream>>>(ket, Ksum);
    kc_kernel<<<NBH, 128, 0, stream>>>(Ksum, Kc);
    ctx_kernel<<<dim3(64, NBH), 256, 0, stream>>>(vtb, ket, ctxT);
    cumsum_kernel<<<dim3(64, NBH), 256, 0, stream>>>(ctxT, ctxc);
    attnout_kernel<<<dim3(64, NBH), 256, 0, stream>>>(qsb, ctxc, Kc, ab);
    gemm_kernel<1><<<dim3(8, 64), 256, 0, stream>>>(ab, Wot + (size_t)d * 1024 * 1024, x, bo + d * DIM, x, TOK, DIM, DIM);
    ln_kernel<<<TOK, 256, 0, stream>>>(x, ln2g + d * DIM, ln2b + d * DIM, hbuf);
    gemm_kernel<2><<<dim3(32, 64), 256, 0, stream>>>(hbuf, W1t + (size_t)d * DFF * 1024, mid, b1 + d * DFF, nullptr, TOK, DFF, DIM);
    gemm_kernel<1><<<dim3(8, 64), 256, 0, stream>>>(mid, W2t + (size_t)d * DFF * 1024, x, b2 + d * DIM, x, TOK, DIM, DFF);
  }
}

// Round 2
// 2648.594 us; speedup vs baseline: 1.1123x; 1.1123x over previous
//
#include <hip/hip_runtime.h>
#include <hip/hip_bf16.h>
#include <stdint.h>

#define TOK 8192      // B*N tokens
#define DIM 1024
#define NSEQ 4096
#define NH 8
#define DHD 128
#define NU 64         // buckets
#define DFF 4096
#define NBH 16        // B*H
#define QKVN 3072     // fused q|k|v width

typedef unsigned short u16;
typedef unsigned int u32;
typedef short bf16x8 __attribute__((ext_vector_type(8)));
typedef float f32x4 __attribute__((ext_vector_type(4)));

__device__ __forceinline__ float bu2f(u16 u) { return __uint_as_float(((u32)u) << 16); }
__device__ __forceinline__ u16 f2bu(float f) {
  union { __hip_bfloat16 b; u16 u; } cv; cv.b = __float2bfloat16(f); return cv.u;
}

typedef __attribute__((address_space(1))) void gvoid_t;
typedef __attribute__((address_space(3))) void lvoid_t;
__device__ __forceinline__ void gload16(void* lds, const void* g) {
#if __has_builtin(__builtin_amdgcn_global_load_lds)
  __builtin_amdgcn_global_load_lds((const gvoid_t*)g, (lvoid_t*)lds, 16, 0, 0);
#else
  const int l = threadIdx.x & 63;
  ((uint4*)lds)[l] = *(const uint4*)g;
#endif
}

// ---------------- weight transpose + fp32->bf16 : W[K][N] -> Wt[rowOff+N][K] ----------------
__global__ __launch_bounds__(256) void wtrans_kernel(const float* __restrict__ W,
    u16* __restrict__ Wt, int K, int N, int dStride, int rowOff)
{
  __shared__ float T[32][33];
  const int tid = threadIdx.x;
  const size_t soff = (size_t)blockIdx.z * K * N;
  const size_t doff = (size_t)blockIdx.z * dStride;
  const int n0 = blockIdx.x << 5, k0 = blockIdx.y << 5;
  const int r = tid >> 3, c4 = (tid & 7) << 2;
  float4 v = *(const float4*)(W + soff + (size_t)(k0 + r) * N + n0 + c4);
  T[r][c4] = v.x; T[r][c4 + 1] = v.y; T[r][c4 + 2] = v.z; T[r][c4 + 3] = v.w;
  __syncthreads();
  u32 lo = (u32)f2bu(T[c4][r]) | ((u32)f2bu(T[c4 + 1][r]) << 16);
  u32 hi = (u32)f2bu(T[c4 + 2][r]) | ((u32)f2bu(T[c4 + 3][r]) << 16);
  *(uint2*)(Wt + doff + (size_t)(rowOff + n0 + r) * K + k0 + c4) = make_uint2(lo, hi);
}

// ---------------- layernorm fp32 -> bf16 ----------------
__global__ __launch_bounds__(256) void ln_kernel(const float* __restrict__ x,
    const float* __restrict__ g, const float* __restrict__ bt, u16* __restrict__ h)
{
  const int row = blockIdx.x, tid = threadIdx.x;
  const int w = tid >> 6, l = tid & 63;
  float4 v = ((const float4*)(x + (size_t)row * DIM))[tid];
  float s = v.x + v.y + v.z + v.w;
  float s2 = v.x * v.x + v.y * v.y + v.z * v.z + v.w * v.w;
#pragma unroll
  for (int off = 32; off; off >>= 1) { s += __shfl_down(s, off); s2 += __shfl_down(s2, off); }
  __shared__ float ps[8];
  __shared__ float mv[2];
  if (l == 0) { ps[w] = s; ps[4 + w] = s2; }
  __syncthreads();
  if (tid == 0) {
    float S = ps[0] + ps[1] + ps[2] + ps[3];
    float S2 = ps[4] + ps[5] + ps[6] + ps[7];
    float mean = S * (1.f / 1024.f);
    float var = S2 * (1.f / 1024.f) - mean * mean;
    mv[0] = mean; mv[1] = rsqrtf(var + 1e-5f);
  }
  __syncthreads();
  const float mean = mv[0], inv = mv[1];
  const int c = tid * 4;
  float o0 = (v.x - mean) * inv * g[c + 0] + bt[c + 0];
  float o1 = (v.y - mean) * inv * g[c + 1] + bt[c + 1];
  float o2 = (v.z - mean) * inv * g[c + 2] + bt[c + 2];
  float o3 = (v.w - mean) * inv * g[c + 3] + bt[c + 3];
  u32 lo = (u32)f2bu(o0) | ((u32)f2bu(o1) << 16);
  u32 hi = (u32)f2bu(o2) | ((u32)f2bu(o3) << 16);
  ((uint2*)(h + (size_t)row * DIM))[tid] = make_uint2(lo, hi);
}

// ---------------- bf16 GEMM, m97 structure + XCD swizzle: A[M][K] x Bt[N][K] -> C[M][N] ----
// EPI 0: C=AB -> bf16 ; EPI 1: C=AB+bias+res -> f32 ; EPI 2: C=gelu(AB+bias) -> bf16
template<int EPI>
__global__ __launch_bounds__(256, 2) void gemm_kernel(
    const u16* __restrict__ A, const u16* __restrict__ Bt, void* Cout,
    const float* __restrict__ bias, const float* res, int M, int N, int K)
{
  __shared__ __align__(16) u16 As[2][128 * 32];
  __shared__ __align__(16) u16 Bs[2][128 * 32];
  const int tid = threadIdx.x;
  const int w = tid >> 6, l = tid & 63;
  // bijective XCD-aware swizzle (m204): each XCD gets a contiguous chunk of
  // row-major tile space -> A-panels L2-resident per XCD.
  const int gx = gridDim.x;
  const int nwg = gx * gridDim.y;
  const int orig = blockIdx.y * gx + blockIdx.x;
  const int qq = nwg >> 3, rr = nwg & 7, xcd = orig & 7, lin = orig >> 3;
  const int wg = (xcd < rr ? xcd * (qq + 1) : rr * (qq + 1) + (xcd - rr) * qq) + lin;
  const int brow = (wg / gx) << 7, bcol = (wg % gx) << 7;
  const int wr = (w >> 1) << 6, wc = (w & 1) << 6;
  const int lr = l & 15, lk = (l >> 4) << 3;
  f32x4 acc[4][4] = {};
  const int nk = K >> 5;

#define STAGE_G(buf, kt)                                                        \
  {                                                                             \
    _Pragma("unroll")                                                           \
    for (int j = 0; j < 2; ++j) {                                               \
      int c = j * 256 + tid;                                                    \
      int rrow = c >> 2, k8 = (c & 3) << 3;                                     \
      int ub = (j * 256 + w * 64) * 8;                                          \
      gload16(&As[buf][ub], A + (size_t)(brow + rrow) * K + (kt) * 32 + k8);    \
      gload16(&Bs[buf][ub], Bt + (size_t)(bcol + rrow) * K + (kt) * 32 + k8);   \
    }                                                                           \
  }

  STAGE_G(0, 0);
  __syncthreads();
  for (int kt = 0; kt < nk; ++kt) {
    int buf = kt & 1;
    if (kt + 1 < nk) STAGE_G(buf ^ 1, kt + 1);
    bf16x8 a[4], bb[4];
#pragma unroll
    for (int m = 0; m < 4; ++m) a[m] = *(const bf16x8*)&As[buf][(wr + m * 16 + lr) * 32 + lk];
#pragma unroll
    for (int n = 0; n < 4; ++n) bb[n] = *(const bf16x8*)&Bs[buf][(wc + n * 16 + lr) * 32 + lk];
#pragma unroll
    for (int m = 0; m < 4; ++m)
#pragma unroll
      for (int n = 0; n < 4; ++n)
        acc[m][n] = __builtin_amdgcn_mfma_f32_16x16x32_bf16(a[m], bb[n], acc[m][n], 0, 0, 0);
    __syncthreads();
  }
#undef STAGE_G
  const int l4 = (l >> 4) << 2;
#pragma unroll
  for (int m = 0; m < 4; ++m) {
#pragma unroll
    for (int n = 0; n < 4; ++n) {
      int col = bcol + wc + n * 16 + lr;
#pragma unroll
      for (int r = 0; r < 4; ++r) {
        int row = brow + wr + m * 16 + l4 + r;
        size_t idx = (size_t)row * N + col;
        float v0 = acc[m][n][r];
        if (EPI == 0) {
          ((u16*)Cout)[idx] = f2bu(v0);
        } else if (EPI == 1) {
          ((float*)Cout)[idx] = v0 + bias[col] + res[idx];
        } else {
          float t = v0 + bias[col];
          ((u16*)Cout)[idx] = f2bu(0.5f * t * (1.0f + erff(t * 0.70710678118654752f)));
        }
      }
    }
  }
}

// ---------------- attention: q softmax (q rows at stride QKVN) ----------------
__global__ __launch_bounds__(256) void qsoftmax_kernel(const u16* __restrict__ qkv, u16* __restrict__ qs)
{
  const int w = threadIdx.x >> 6, l = threadIdx.x & 63;
  const size_t gid = (size_t)blockIdx.x * 4 + w;
  const size_t tok = gid >> 3;
  const int h = (int)(gid & 7);
  const u16* row = qkv + tok * QKVN + h * 128;
  u16* orow = qs + tok * DIM + h * 128;
  u32 p = *(const u32*)(row + l * 2);
  float f0 = bu2f((u16)(p & 0xffff)), f1 = bu2f((u16)(p >> 16));
  float m = fmaxf(f0, f1);
#pragma unroll
  for (int off = 32; off; off >>= 1) m = fmaxf(m, __shfl_xor(m, off));
  float e0 = expf(f0 - m), e1 = expf(f1 - m);
  float s = e0 + e1;
#pragma unroll
  for (int off = 32; off; off >>= 1) s += __shfl_xor(s, off);
  float sc = 0.08838834764831845f / s;   // (1/sqrt(128)) / sum
  u32 o = (u32)f2bu(e0 * sc) | ((u32)f2bu(e1 * sc) << 16);
  *(u32*)(orow + l * 2) = o;
}

// ---------------- exp(k), v : rows at stride QKVN -> transposed [bh][e][n] bf16 ----------------
__global__ __launch_bounds__(256) void kvt_kernel(
    const u16* __restrict__ kin, const u16* __restrict__ vin,
    u16* __restrict__ ket, u16* __restrict__ vt)
{
  __shared__ u16 T[128 * 72];
  const int tid = threadIdx.x;
  const int t64 = blockIdx.x, bh = blockIdx.y;
  const int b = bh >> 3, h = bh & 7;
  for (int pass = 0; pass < 2; ++pass) {
    const u16* src = pass ? vin : kin;
    u16* dst = pass ? vt : ket;
    if (pass) __syncthreads();
#pragma unroll
    for (int j = 0; j < 4; ++j) {
      int c = j * 256 + tid;
      int i = c >> 4, e8 = (c & 15) << 3;
      bf16x8 dv = *(const bf16x8*)(src + ((size_t)(b * NSEQ + t64 * 64 + i)) * QKVN + h * 128 + e8);
#pragma unroll
      for (int jj = 0; jj < 8; ++jj) {
        float f = bu2f((u16)dv[jj]);
        if (pass == 0) f = expf(f);
        T[(e8 + jj) * 72 + i] = f2bu(f);
      }
    }
    __syncthreads();
#pragma unroll
    for (int j = 0; j < 4; ++j) {
      int c = j * 256 + tid;
      int e = c >> 3, n8 = (c & 7) << 3;
      bf16x8 o;
#pragma unroll
      for (int jj = 0; jj < 8; ++jj) o[jj] = (short)T[e * 72 + n8 + jj];
      *(bf16x8*)(dst + ((size_t)(bh * 128 + e)) * NSEQ + t64 * 64 + n8) = o;
    }
  }
}

// ---------------- per-bucket k sums ----------------
__global__ void ksum_kernel(const u16* __restrict__ ket, float* __restrict__ Ksum)
{
  const int u = blockIdx.x, bh = blockIdx.y, e = threadIdx.x;  // 128 threads
  const u16* p = ket + ((size_t)(bh * 128 + e)) * NSEQ + u * 64;
  float s = 0.f;
#pragma unroll
  for (int i = 0; i < 64; ++i) s += bu2f(p[i]);
  Ksum[(((size_t)bh * 64 + u) << 7) + e] = s;
}

// ---------------- exclusive cumsum of k sums over buckets ----------------
__global__ void kc_kernel(const float* __restrict__ Ksum, float* __restrict__ Kc)
{
  const int bh = blockIdx.x, e = threadIdx.x;
  float run = 0.f;
  for (int u = 0; u < 64; ++u) {
    size_t i = (((size_t)bh * 64 + u) << 7) + e;
    Kc[i] = run;
    run += Ksum[i];
  }
}

// ---------------- per-bucket ctx^T[e][d] = sum_i v[i,e]*ke[i,d] (MFMA) ----------------
__global__ __launch_bounds__(256, 2) void ctx_kernel(
    const u16* __restrict__ vt, const u16* __restrict__ ket, u16* __restrict__ ctxT)
{
  __shared__ __align__(16) u16 Av[128 * 64];
  __shared__ __align__(16) u16 Bk[128 * 64];
  const int tid = threadIdx.x, w = tid >> 6, l = tid & 63;
  const int u = blockIdx.x, bh = blockIdx.y;
  const int lr = l & 15, lk = (l >> 4) << 3;
#pragma unroll
  for (int j = 0; j < 4; ++j) {
    int c = j * 256 + tid;
    int row = c >> 3, i8 = (c & 7) << 3;
    size_t goff = ((size_t)(bh * 128 + row)) * NSEQ + u * 64 + i8;
    int ub = (j * 256 + w * 64) * 8;
    gload16(&Av[ub], vt + goff);
    gload16(&Bk[ub], ket + goff);
  }
  __syncthreads();
  const int wr = (w >> 1) << 6, wc = (w & 1) << 6;
  f32x4 acc[4][4] = {};
#pragma unroll
  for (int ks = 0; ks < 2; ++ks) {
    bf16x8 a[4], bb[4];
#pragma unroll
    for (int m = 0; m < 4; ++m) a[m] = *(const bf16x8*)&Av[(wr + m * 16 + lr) * 64 + ks * 32 + lk];
#pragma unroll
    for (int n = 0; n < 4; ++n) bb[n] = *(const bf16x8*)&Bk[(wc + n * 16 + lr) * 64 + ks * 32 + lk];
#pragma unroll
    for (int m = 0; m < 4; ++m)
#pragma unroll
      for (int n = 0; n < 4; ++n)
        acc[m][n] = __builtin_amdgcn_mfma_f32_16x16x32_bf16(a[m], bb[n], acc[m][n], 0, 0, 0);
  }
  u16* out = ctxT + ((size_t)(bh * 64 + u) << 14);
  const int l4 = (l >> 4) << 2;
#pragma unroll
  for (int m = 0; m < 4; ++m)
#pragma unroll
    for (int n = 0; n < 4; ++n)
#pragma unroll
      for (int r = 0; r < 4; ++r) {
        int e = wr + m * 16 + l4 + r, d = wc + n * 16 + lr;
        out[e * 128 + d] = f2bu(acc[m][n][r]);
      }
}

// ---------------- exclusive cumsum of ctx over buckets ----------------
__global__ void cumsum_kernel(const u16* __restrict__ ctxT, u16* __restrict__ ctxc)
{
  const size_t base = ((size_t)blockIdx.y << 20) + (size_t)blockIdx.x * 256 + threadIdx.x;
  const u16* src = ctxT + base;
  u16* dst = ctxc + base;
  float run = 0.f;
  for (int u = 0; u < 64; ++u) {
    u16 cvv = src[(size_t)u << 14];
    dst[(size_t)u << 14] = f2bu(run);
    run += bu2f(cvv);
  }
}

// ---------------- out[n][e] = D_inv[n] * sum_d qs[n,d]*ctxc[d][e] (MFMA) ----------------
__global__ __launch_bounds__(256, 2) void attnout_kernel(
    const u16* __restrict__ qs, const u16* __restrict__ ctxc,
    const float* __restrict__ Kc, u16* __restrict__ aout)
{
  __shared__ __align__(16) u16 Aq[64 * 128];
  __shared__ __align__(16) u16 Bc[128 * 128];
  __shared__ float KcS[128];
  __shared__ float Dinv[64];
  const int tid = threadIdx.x, w = tid >> 6, l = tid & 63;
  const int u = blockIdx.x, bh = blockIdx.y;
  const int b = bh >> 3, h = bh & 7;
  const int lr = l & 15, lk = (l >> 4) << 3;
#pragma unroll
  for (int j = 0; j < 4; ++j) {
    int c = j * 256 + tid;
    int n = c >> 4, d8 = (c & 15) << 3;
    gload16(&Aq[(j * 256 + w * 64) * 8],
            qs + ((size_t)(b * NSEQ + u * 64 + n)) * DIM + h * 128 + d8);
  }
  const u16* csrc = ctxc + ((size_t)(bh * 64 + u) << 14);
#pragma unroll
  for (int j = 0; j < 8; ++j) {
    int c = j * 256 + tid;
    gload16(&Bc[(j * 256 + w * 64) * 8], csrc + (size_t)c * 8);
  }
  if (tid < 128) KcS[tid] = Kc[(((size_t)bh * 64 + u) << 7) + tid];
  __syncthreads();
  if (tid < 64) {
    float s = 0.f;
#pragma unroll
    for (int dd = 0; dd < 128; ++dd) {
      int d = (dd + tid * 2) & 127;   // rotate to dodge LDS bank conflicts
      s += bu2f(Aq[tid * 128 + d]) * KcS[d];
    }
    Dinv[tid] = 1.f / fmaxf(s, 1e-3f);
  }
  __syncthreads();
  f32x4 acc[4][2] = {};
#pragma unroll
  for (int ks = 0; ks < 4; ++ks) {
    bf16x8 a[4], bb[2];
#pragma unroll
    for (int m = 0; m < 4; ++m) a[m] = *(const bf16x8*)&Aq[(m * 16 + lr) * 128 + ks * 32 + lk];
#pragma unroll
    for (int n = 0; n < 2; ++n) bb[n] = *(const bf16x8*)&Bc[(w * 32 + n * 16 + lr) * 128 + ks * 32 + lk];
#pragma unroll
    for (int m = 0; m < 4; ++m)
#pragma unroll
      for (int n = 0; n < 2; ++n)
        acc[m][n] = __builtin_amdgcn_mfma_f32_16x16x32_bf16(a[m], bb[n], acc[m][n], 0, 0, 0);
  }
  const int l4 = (l >> 4) << 2;
#pragma unroll
  for (int m = 0; m < 4; ++m)
#pragma unroll
    for (int n = 0; n < 2; ++n)
#pragma unroll
      for (int r = 0; r < 4; ++r) {
        int nrow = m * 16 + l4 + r;
        int e = w * 32 + n * 16 + lr;
        float v = acc[m][n][r] * Dinv[nrow];
        aout[((size_t)(b * NSEQ + u * 64 + nrow)) * DIM + h * 128 + e] = f2bu(v);
      }
}

extern "C" void kernel_launch(void* const* d_in, const int* in_sizes, int n_in,
                              void* d_out, int out_size, void* d_ws, size_t ws_size,
                              hipStream_t stream)
{
  (void)in_sizes; (void)n_in; (void)out_size; (void)ws_size;
  const float* x_in = (const float*)d_in[0];
  const float* ln1g = (const float*)d_in[1];
  const float* ln1b = (const float*)d_in[2];
  const float* Wq   = (const float*)d_in[3];
  const float* Wk   = (const float*)d_in[4];
  const float* Wv   = (const float*)d_in[5];
  const float* Wo   = (const float*)d_in[6];
  const float* bo   = (const float*)d_in[7];
  const float* ln2g = (const float*)d_in[8];
  const float* ln2b = (const float*)d_in[9];
  const float* W1   = (const float*)d_in[10];
  const float* b1   = (const float*)d_in[11];
  const float* W2   = (const float*)d_in[12];
  const float* b2   = (const float*)d_in[13];
  float* x = (float*)d_out;

  char* ws = (char*)d_ws;
  size_t off = 0;
  auto alloc = [&](size_t bytes) -> char* {
    char* p = ws + off;
    off += (bytes + 255) & ~(size_t)255;
    return p;
  };
  const size_t SW = (size_t)6 * 1024 * 1024;   // small weight elems (per 6 layers)
  const size_t BW = (size_t)6 * 4096 * 1024;   // big weight elems
  u16* Wqkvt = (u16*)alloc(SW * 3 * 2);        // fused [6][3072][1024]
  u16* Wot = (u16*)alloc(SW * 2);
  u16* W1t = (u16*)alloc(BW * 2);
  u16* W2t = (u16*)alloc(BW * 2);
  u16* hbuf = (u16*)alloc((size_t)TOK * DIM * 2);
  u16* qsb  = (u16*)alloc((size_t)TOK * DIM * 2);
  u16* ket  = (u16*)alloc((size_t)TOK * DIM * 2);
  u16* vtb  = (u16*)alloc((size_t)TOK * DIM * 2);
  u16* ab   = (u16*)alloc((size_t)TOK * DIM * 2);
  float* Ksum = (float*)alloc((size_t)NBH * 64 * 128 * 4);
  float* Kc   = (float*)alloc((size_t)NBH * 64 * 128 * 4);
  char* R = alloc((size_t)TOK * DFF * 2);      // 67MB union region
  u16* qkvb = (u16*)R;                                   // phase 1: fused qkv bf16 [8192][3072]
  u16* ctxT = (u16*)R;                                   // phase 2: ctx buffers
  u16* ctxc = (u16*)(R + ((size_t)NBH * 64 * 128 * 128) * 2);
  u16* mid  = (u16*)R;                                   // phase 3: ffn mid

  // one-time (per call) weight transpose + bf16 conversion
  wtrans_kernel<<<dim3(32, 32, 6), 256, 0, stream>>>(Wq, Wqkvt, 1024, 1024, QKVN * 1024, 0);
  wtrans_kernel<<<dim3(32, 32, 6), 256, 0, stream>>>(Wk, Wqkvt, 1024, 1024, QKVN * 1024, 1024);
  wtrans_kernel<<<dim3(32, 32, 6), 256, 0, stream>>>(Wv, Wqkvt, 1024, 1024, QKVN * 1024, 2048);
  wtrans_kernel<<<dim3(32, 32, 6), 256, 0, stream>>>(Wo, Wot, 1024, 1024, 1024 * 1024, 0);
  wtrans_kernel<<<dim3(128, 32, 6), 256, 0, stream>>>(W1, W1t, 1024, 4096, 4096 * 1024, 0);
  wtrans_kernel<<<dim3(32, 128, 6), 256, 0, stream>>>(W2, W2t, 4096, 1024, 4096 * 1024, 0);
  hipMemcpyAsync(x, x_in, (size_t)TOK * DIM * 4, hipMemcpyDeviceToDevice, stream);

  for (int d = 0; d < 6; ++d) {
    ln_kernel<<<TOK, 256, 0, stream>>>(x, ln1g + d * DIM, ln1b + d * DIM, hbuf);
    gemm_kernel<0><<<dim3(24, 64), 256, 0, stream>>>(hbuf, Wqkvt + (size_t)d * QKVN * 1024, qkvb, nullptr, nullptr, TOK, QKVN, DIM);
    qsoftmax_kernel<<<TOK * NH / 4, 256, 0, stream>>>(qkvb, qsb);
    kvt_kernel<<<dim3(64, NBH), 256, 0, stream>>>(qkvb + 1024, qkvb + 2048, ket, vtb);
    ksum_kernel<<<dim3(64, NBH), 128, 0, stream>>>(ket, Ksum);
    kc_kernel<<<NBH, 128, 0, stream>>>(Ksum, Kc);
    ctx_kernel<<<dim3(64, NBH), 256, 0, stream>>>(vtb, ket, ctxT);
    cumsum_kernel<<<dim3(64, NBH), 256, 0, stream>>>(ctxT, ctxc);
    attnout_kernel<<<dim3(64, NBH), 256, 0, stream>>>(qsb, ctxc, Kc, ab);
    gemm_kernel<1><<<dim3(8, 64), 256, 0, stream>>>(ab, Wot + (size_t)d * 1024 * 1024, x, bo + d * DIM, x, TOK, DIM, DIM);
    ln_kernel<<<TOK, 256, 0, stream>>>(x, ln2g + d * DIM, ln2b + d * DIM, hbuf);
    gemm_kernel<2><<<dim3(32, 64), 256, 0, stream>>>(hbuf, W1t + (size_t)d * DFF * 1024, mid, b1 + d * DFF, nullptr, TOK, DFF, DIM);
    gemm_kernel<1><<<dim3(8, 64), 256, 0, stream>>>(mid, W2t + (size_t)d * DFF * 1024, x, b2 + d * DIM, x, TOK, DIM, DFF);
  }
}